// Round 3
// baseline (1609.224 us; speedup 1.0000x reference)
//
#include <hip/hip_runtime.h>
#include <math.h>

#define N_NODES 100000
#define N_EDGES 3200000
#define NEG 0.2f

__device__ __forceinline__ float lrelu(float x){ return x > 0.f ? x : NEG * x; }
// packed bf16 pair in a uint: low / high element -> fp32
__device__ __forceinline__ float bflo(unsigned int u){
  union { unsigned int i; float f; } v; v.i = u << 16; return v.f;
}
__device__ __forceinline__ float bfhi(unsigned int u){
  union { unsigned int i; float f; } v; v.i = u & 0xffff0000u; return v.f;
}
// fp32 -> bf16 (RNE)
__device__ __forceinline__ unsigned short f2bf(float f){
  union { float f; unsigned int i; } v; v.f = f;
  unsigned int r = v.i + 0x7fffu + ((v.i >> 16) & 1u);
  return (unsigned short)(r >> 16);
}
__device__ __forceinline__ unsigned int packbf(float lo, float hi){
  return (unsigned int)f2bf(lo) | ((unsigned int)f2bf(hi) << 16);
}

// ---------- GEMM 1: fp32 A[M,K] @ fp32 B[K,N] -> bf16 C. N,K multiples of 64 ----------
__global__ __launch_bounds__(256) void k_gemm_f_obf(const float* __restrict__ A,
                                                    const float* __restrict__ B,
                                                    unsigned short* __restrict__ C,
                                                    int M, int N, int K){
  __shared__ float As[64][68];  // As[k][row], pad 68
  __shared__ float Bs[64][68];  // Bs[k][col]
  const int tid = threadIdx.x;
  const int tx = tid & 15, ty = tid >> 4;
  const int r0 = blockIdx.x * 64, c0 = blockIdx.y * 64;
  const int lr = tid >> 4;          // 0..15
  const int lk = (tid & 15) * 4;    // 0..60
  float acc[4][4] = {};
  for (int kk = 0; kk < K; kk += 64){
    #pragma unroll
    for (int rr = 0; rr < 64; rr += 16){
      int row = r0 + lr + rr;
      float4 av = make_float4(0.f,0.f,0.f,0.f);
      if (row < M) av = *(const float4*)(A + (size_t)row*K + kk + lk);
      As[lk+0][lr+rr]=av.x; As[lk+1][lr+rr]=av.y;
      As[lk+2][lr+rr]=av.z; As[lk+3][lr+rr]=av.w;
      int krow = lr + rr;
      *(float4*)(&Bs[krow][lk]) = *(const float4*)(B + (size_t)(kk+krow)*N + c0 + lk);
    }
    __syncthreads();
    #pragma unroll
    for (int k = 0; k < 64; ++k){
      float4 a = *(const float4*)(&As[k][ty*4]);
      float4 b = *(const float4*)(&Bs[k][tx*4]);
      float av[4] = {a.x,a.y,a.z,a.w};
      float bv[4] = {b.x,b.y,b.z,b.w};
      #pragma unroll
      for (int i=0;i<4;++i)
        #pragma unroll
        for (int j=0;j<4;++j) acc[i][j] += av[i]*bv[j];
    }
    __syncthreads();
  }
  #pragma unroll
  for (int i=0;i<4;++i){
    int row = r0 + ty*4 + i;
    if (row < M){
      uint2 o;
      o.x = packbf(acc[i][0], acc[i][1]);
      o.y = packbf(acc[i][2], acc[i][3]);
      *(uint2*)(C + (size_t)row*N + c0 + tx*4) = o;
    }
  }
}

// ---------- GEMM 2: bf16 A[M,K] @ fp32 B[K,N] -> fp32 C. N,K multiples of 64 ----------
__global__ __launch_bounds__(256) void k_gemm_bf_f(const unsigned short* __restrict__ A,
                                                   const float* __restrict__ B,
                                                   float* __restrict__ C,
                                                   int M, int N, int K){
  __shared__ float As[64][68];
  __shared__ float Bs[64][68];
  const int tid = threadIdx.x;
  const int tx = tid & 15, ty = tid >> 4;
  const int r0 = blockIdx.x * 64, c0 = blockIdx.y * 64;
  const int lr = tid >> 4;
  const int lk = (tid & 15) * 4;
  float acc[4][4] = {};
  for (int kk = 0; kk < K; kk += 64){
    #pragma unroll
    for (int rr = 0; rr < 64; rr += 16){
      int row = r0 + lr + rr;
      float a0=0.f,a1=0.f,a2=0.f,a3=0.f;
      if (row < M){
        uint2 av = *(const uint2*)(A + (size_t)row*K + kk + lk);
        a0=bflo(av.x); a1=bfhi(av.x); a2=bflo(av.y); a3=bfhi(av.y);
      }
      As[lk+0][lr+rr]=a0; As[lk+1][lr+rr]=a1;
      As[lk+2][lr+rr]=a2; As[lk+3][lr+rr]=a3;
      int krow = lr + rr;
      *(float4*)(&Bs[krow][lk]) = *(const float4*)(B + (size_t)(kk+krow)*N + c0 + lk);
    }
    __syncthreads();
    #pragma unroll
    for (int k = 0; k < 64; ++k){
      float4 a = *(const float4*)(&As[k][ty*4]);
      float4 b = *(const float4*)(&Bs[k][tx*4]);
      float av[4] = {a.x,a.y,a.z,a.w};
      float bv[4] = {b.x,b.y,b.z,b.w};
      #pragma unroll
      for (int i=0;i<4;++i)
        #pragma unroll
        for (int j=0;j<4;++j) acc[i][j] += av[i]*bv[j];
    }
    __syncthreads();
  }
  #pragma unroll
  for (int i=0;i<4;++i){
    int row = r0 + ty*4 + i;
    if (row < M)
      *(float4*)(C + (size_t)row*N + c0 + tx*4) =
        make_float4(acc[i][0],acc[i][1],acc[i][2],acc[i][3]);
  }
}

// ---------- layer-1 scores: el/er (N,4) from bf16 feat (N,4,128), fp32 al/ar ----------
__global__ __launch_bounds__(256) void k_score1(const unsigned short* __restrict__ feat,
    const float* __restrict__ al, const float* __restrict__ ar,
    float* __restrict__ el, float* __restrict__ er){
  int wave = threadIdx.x >> 6, lane = threadIdx.x & 63;
  int n = blockIdx.x*4 + wave;
  if (n >= N_NODES) return;
  int h = lane >> 4;               // head
  int d = h*128 + (lane & 15)*8;   // 8 contiguous elems per lane
  uint4 f = *(const uint4*)(feat + (size_t)n*512 + d);
  float4 a0 = *(const float4*)(al + d), a1 = *(const float4*)(al + d + 4);
  float4 r0 = *(const float4*)(ar + d), r1 = *(const float4*)(ar + d + 4);
  float fv[8] = {bflo(f.x),bfhi(f.x),bflo(f.y),bfhi(f.y),
                 bflo(f.z),bfhi(f.z),bflo(f.w),bfhi(f.w)};
  float se = fv[0]*a0.x+fv[1]*a0.y+fv[2]*a0.z+fv[3]*a0.w
           + fv[4]*a1.x+fv[5]*a1.y+fv[6]*a1.z+fv[7]*a1.w;
  float sr = fv[0]*r0.x+fv[1]*r0.y+fv[2]*r0.z+fv[3]*r0.w
           + fv[4]*r1.x+fv[5]*r1.y+fv[6]*r1.z+fv[7]*r1.w;
  #pragma unroll
  for (int m=1;m<16;m<<=1){ se += __shfl_xor(se,m); sr += __shfl_xor(sr,m); }
  if ((lane&15)==0){ el[n*4+h]=se; er[n*4+h]=sr; }
}

// ---------- layer-2 scores: el/er (N,) from fp32 feat (N,64), fp32 al/ar ----------
__global__ __launch_bounds__(256) void k_score2(const float* __restrict__ feat,
    const float* __restrict__ al, const float* __restrict__ ar,
    float* __restrict__ el, float* __restrict__ er){
  int wave = threadIdx.x >> 6, lane = threadIdx.x & 63;
  int n = blockIdx.x*4 + wave;
  if (n >= N_NODES) return;
  float v = feat[(size_t)n*64 + lane];
  float se = v * al[lane], sr = v * ar[lane];
  #pragma unroll
  for (int m=1;m<64;m<<=1){ se += __shfl_xor(se,m); sr += __shfl_xor(sr,m); }
  if (lane==0){ el[n]=se; er[n]=sr; }
}

// ---------- CSR build ----------
__global__ void k_zero(int* __restrict__ p, int n){
  int i = blockIdx.x*blockDim.x + threadIdx.x;
  if (i < n) p[i] = 0;
}

__global__ void k_count(const int* __restrict__ dst, int* __restrict__ deg){
  int e = blockIdx.x*blockDim.x + threadIdx.x;
  if (e < N_EDGES) atomicAdd(&deg[dst[e]], 1);
}

__global__ __launch_bounds__(1024) void k_scan1(const int* __restrict__ deg,
    int* __restrict__ indptr, int* __restrict__ bsum){
  __shared__ int lds[1024];
  int t = threadIdx.x, i = blockIdx.x*1024 + t;
  int v = (i < N_NODES) ? deg[i] : 0;
  lds[t] = v; __syncthreads();
  for (int off=1; off<1024; off<<=1){
    int u = (t>=off)? lds[t-off] : 0;
    __syncthreads();
    lds[t] += u;
    __syncthreads();
  }
  if (i < N_NODES) indptr[i] = lds[t] - v;     // exclusive
  if (t == 1023) bsum[blockIdx.x] = lds[1023];
}

__global__ void k_scan2(const int* __restrict__ bsum, int* __restrict__ boff, int nb){
  __shared__ int lds[128];
  int t = threadIdx.x;
  int v = (t < nb) ? bsum[t] : 0;
  lds[t] = v; __syncthreads();
  for (int off=1; off<128; off<<=1){
    int u = (t>=off)? lds[t-off] : 0;
    __syncthreads();
    lds[t] += u;
    __syncthreads();
  }
  if (t < nb) boff[t] = lds[t] - v;
}

__global__ void k_scan3(int* __restrict__ indptr, const int* __restrict__ boff){
  int i = blockIdx.x*blockDim.x + threadIdx.x;
  if (i < N_NODES) indptr[i] += boff[i>>10];
  if (i == N_NODES) indptr[N_NODES] = N_EDGES;
}

__global__ void k_copy(const int* __restrict__ a, int* __restrict__ b){
  int i = blockIdx.x*blockDim.x + threadIdx.x;
  if (i < N_NODES) b[i] = a[i];
}

__global__ void k_scatter(const int* __restrict__ src, const int* __restrict__ dst,
                          int* __restrict__ cursor, int* __restrict__ csr_src){
  int e = blockIdx.x*blockDim.x + threadIdx.x;
  if (e < N_EDGES){
    int d = dst[e];
    int pos = atomicAdd(&cursor[d], 1);
    csr_src[pos] = src[e];
  }
}

// ---------- layer-1 softmax + aggregate + ELU: wave per dst node, bf16 feat/out ----------
__global__ __launch_bounds__(256) void k_agg1(const unsigned short* __restrict__ feat,
    const float* __restrict__ el, const float* __restrict__ er,
    const int* __restrict__ indptr, const int* __restrict__ csr_src,
    unsigned short* __restrict__ out){
  int wave = threadIdx.x >> 6, lane = threadIdx.x & 63;
  int n = blockIdx.x*4 + wave;
  if (n >= N_NODES) return;
  int p0 = indptr[n], p1 = indptr[n+1];
  float4 ev = *(const float4*)(er + n*4);
  float erh[4] = {ev.x, ev.y, ev.z, ev.w};
  // pass 1: softmax denominators (|e| <= ~12: exp safe without max-shift)
  float s4[4] = {0.f,0.f,0.f,0.f};
  for (int e = p0 + lane; e < p1; e += 64){
    int s = csr_src[e];
    float4 lv = *(const float4*)(el + s*4);
    s4[0] += __expf(lrelu(lv.x + erh[0]));
    s4[1] += __expf(lrelu(lv.y + erh[1]));
    s4[2] += __expf(lrelu(lv.z + erh[2]));
    s4[3] += __expf(lrelu(lv.w + erh[3]));
  }
  #pragma unroll
  for (int m=1;m<64;m<<=1){
    s4[0]+=__shfl_xor(s4[0],m); s4[1]+=__shfl_xor(s4[1],m);
    s4[2]+=__shfl_xor(s4[2],m); s4[3]+=__shfl_xor(s4[3],m);
  }
  int hh = lane >> 4;
  float inv  = s4[hh] > 0.f ? 1.f/s4[hh] : 0.f;
  float myer = erh[hh];
  // pass 2: weighted gather, 8 contiguous bf16 per lane (1KB/edge, coalesced)
  float acc[8] = {0.f,0.f,0.f,0.f,0.f,0.f,0.f,0.f};
  const int d0 = lane*8;
  for (int e = p0; e < p1; ++e){
    int s = csr_src[e];
    float alpha = __expf(lrelu(el[s*4+hh] + myer)) * inv;
    uint4 q = *(const uint4*)(feat + (size_t)s*512 + d0);
    acc[0]+=alpha*bflo(q.x); acc[1]+=alpha*bfhi(q.x);
    acc[2]+=alpha*bflo(q.y); acc[3]+=alpha*bfhi(q.y);
    acc[4]+=alpha*bflo(q.z); acc[5]+=alpha*bfhi(q.z);
    acc[6]+=alpha*bflo(q.w); acc[7]+=alpha*bfhi(q.w);
  }
  // fused ELU + bf16 store
  #pragma unroll
  for (int i=0;i<8;++i) acc[i] = acc[i]>0.f ? acc[i] : __expf(acc[i])-1.f;
  uint4 o;
  o.x = packbf(acc[0],acc[1]); o.y = packbf(acc[2],acc[3]);
  o.z = packbf(acc[4],acc[5]); o.w = packbf(acc[6],acc[7]);
  *(uint4*)(out + (size_t)n*512 + d0) = o;
}

// ---------- layer-2 softmax + aggregate: wave per dst node, fp32 feat, fp32 out ----------
__global__ __launch_bounds__(256) void k_agg2(const float* __restrict__ feat,
    const float* __restrict__ el, const float* __restrict__ er,
    const int* __restrict__ indptr, const int* __restrict__ csr_src,
    float* __restrict__ out){
  int wave = threadIdx.x >> 6, lane = threadIdx.x & 63;
  int n = blockIdx.x*4 + wave;
  if (n >= N_NODES) return;
  int p0 = indptr[n], p1 = indptr[n+1];
  float ern = er[n];
  float ssum = 0.f;
  for (int e = p0 + lane; e < p1; e += 64)
    ssum += __expf(lrelu(el[csr_src[e]] + ern));
  #pragma unroll
  for (int m=1;m<64;m<<=1) ssum += __shfl_xor(ssum,m);
  float inv = ssum > 0.f ? 1.f/ssum : 0.f;
  float acc = 0.f;
  for (int e = p0; e < p1; ++e){
    int s = csr_src[e];
    float alpha = __expf(lrelu(el[s] + ern)) * inv;
    acc += alpha * feat[(size_t)s*64 + lane];
  }
  out[(size_t)n*64 + lane] = acc;
}

extern "C" void kernel_launch(void* const* d_in, const int* in_sizes, int n_in,
                              void* d_out, int out_size, void* d_ws, size_t ws_size,
                              hipStream_t stream){
  const float* x   = (const float*)d_in[0];
  const float* W1  = (const float*)d_in[1];
  const float* al1 = (const float*)d_in[2];
  const float* ar1 = (const float*)d_in[3];
  const float* W2  = (const float*)d_in[4];
  const float* al2 = (const float*)d_in[5];
  const float* ar2 = (const float*)d_in[6];
  const int* src   = (const int*)d_in[7];
  const int* dst   = (const int*)d_in[8];
  float* out = (float*)d_out;

  char* ws = (char*)d_ws;
  size_t off = 0;
  auto alloc = [&](size_t bytes)->char*{
    char* p = ws + off; off += (bytes + 255) & ~(size_t)255; return p;
  };
  unsigned short* feat1 = (unsigned short*)alloc((size_t)N_NODES*512*2); // 102.4 MB
  unsigned short* h1    = (unsigned short*)alloc((size_t)N_NODES*512*2); // 102.4 MB
  float* feat2 = (float*)feat1;   // alias: feat1 dead after k_agg1 (25.6 MB needed)
  float* el1   = (float*)alloc((size_t)N_NODES*4*4);
  float* er1   = (float*)alloc((size_t)N_NODES*4*4);
  float* el2   = (float*)alloc((size_t)N_NODES*4);
  float* er2   = (float*)alloc((size_t)N_NODES*4);
  int*   deg     = (int*)alloc((size_t)N_NODES*4);
  int*   indptr  = (int*)alloc((size_t)(N_NODES+1)*4);
  int*   cursor  = (int*)alloc((size_t)N_NODES*4);
  int*   bsum    = (int*)alloc(512);
  int*   boff    = (int*)alloc(512);
  int*   csr_src = (int*)alloc((size_t)N_EDGES*4);                       // 12.8 MB
  // total ~222 MB (proven < ws_size in round 2)

  dim3 b256(256);
  k_zero<<<dim3((N_NODES+255)/256), b256, 0, stream>>>(deg, N_NODES);
  // layer 1: feat1 = x @ W1 (bf16 out)
  k_gemm_f_obf<<<dim3(1563, 8), b256, 0, stream>>>(x, W1, feat1, N_NODES, 512, 128);
  k_score1<<<dim3(25000), b256, 0, stream>>>(feat1, al1, ar1, el1, er1);
  // dst-CSR (shared by both layers)
  k_count<<<dim3((N_EDGES+255)/256), b256, 0, stream>>>(dst, deg);
  k_scan1<<<dim3(98), dim3(1024), 0, stream>>>(deg, indptr, bsum);
  k_scan2<<<dim3(1), dim3(128), 0, stream>>>(bsum, boff, 98);
  k_scan3<<<dim3((N_NODES+256)/256), b256, 0, stream>>>(indptr, boff);
  k_copy<<<dim3((N_NODES+255)/256), b256, 0, stream>>>(indptr, cursor);
  k_scatter<<<dim3((N_EDGES+255)/256), b256, 0, stream>>>(src, dst, cursor, csr_src);
  // layer-1 aggregate + ELU -> h1 (bf16)
  k_agg1<<<dim3(25000), b256, 0, stream>>>(feat1, el1, er1, indptr, csr_src, h1);
  // layer 2: feat2 = h1 @ W2 (fp32, aliases feat1)
  k_gemm_bf_f<<<dim3(1563, 1), b256, 0, stream>>>(h1, W2, feat2, N_NODES, 64, 512);
  k_score2<<<dim3(25000), b256, 0, stream>>>(feat2, al2, ar2, el2, er2);
  k_agg2<<<dim3(25000), b256, 0, stream>>>(feat2, el2, er2, indptr, csr_src, out);
}

// Round 5
// 1480.275 us; speedup vs baseline: 1.0871x; 1.0871x over previous
//
#include <hip/hip_runtime.h>
#include <math.h>

#define N_NODES 100000
#define N_EDGES 3200000
#define NEG 0.2f

typedef __attribute__((ext_vector_type(8))) short short8;
typedef __attribute__((ext_vector_type(4))) float f32x4;

__device__ __forceinline__ float lrelu(float x){ return x > 0.f ? x : NEG * x; }
__device__ __forceinline__ float bflo(unsigned int u){
  union { unsigned int i; float f; } v; v.i = u << 16; return v.f;
}
__device__ __forceinline__ float bfhi(unsigned int u){
  union { unsigned int i; float f; } v; v.i = u & 0xffff0000u; return v.f;
}
__device__ __forceinline__ float bfus(unsigned short u){
  union { unsigned int i; float f; } v; v.i = ((unsigned int)u) << 16; return v.f;
}
__device__ __forceinline__ unsigned short f2bf(float f){
  union { float f; unsigned int i; } v; v.f = f;
  unsigned int r = v.i + 0x7fffu + ((v.i >> 16) & 1u);
  return (unsigned short)(r >> 16);
}
__device__ __forceinline__ unsigned int packbf(float lo, float hi){
  return (unsigned int)f2bf(lo) | ((unsigned int)f2bf(hi) << 16);
}

// ---- weight prep: W1 [128][512] fp32 -> W1t [512][128] bf16 (n-major) ----
__global__ void k_cvtW1(const float* __restrict__ W, unsigned short* __restrict__ Wt){
  int i = blockIdx.x*256 + threadIdx.x;
  if (i < 512*128){ int n = i >> 7, k = i & 127; Wt[i] = f2bf(W[k*512 + n]); }
}
// ---- W2 [512][64] fp32 -> W2t [64][512] bf16 ----
__global__ void k_cvtW2(const float* __restrict__ W, unsigned short* __restrict__ Wt){
  int i = blockIdx.x*256 + threadIdx.x;
  if (i < 64*512){ int n = i >> 9, k = i & 511; Wt[i] = f2bf(W[k*64 + n]); }
}

// ---- GEMM1 (MFMA): x fp32 [M][128] @ W1t bf16 -> feat1h bf16 [4][M][128] ----
// block 256 (4 waves), tile 128(M) x 128(N); N-tile == one head. BK=64, 2 iters.
__global__ __launch_bounds__(256) void k_mm1(const float* __restrict__ A,
    const unsigned short* __restrict__ Bt,
    unsigned short* __restrict__ C, int M){
  __shared__ unsigned short sm[18432];          // As 128x72 | Bs 128x72 (36.9 KB)
  unsigned short* As = sm;
  unsigned short* Bs = sm + 9216;
  const int t = threadIdx.x;
  const int w = t >> 6, l = t & 63;
  const int quad = l >> 4, l16 = l & 15;
  const int m0 = blockIdx.x * 128;
  const int head = blockIdx.y;
  const int moff = (w & 1) * 64, noff = (w >> 1) * 64;
  f32x4 acc[4][4];
  #pragma unroll
  for (int i=0;i<4;++i)
    #pragma unroll
    for (int j=0;j<4;++j){ acc[i][j][0]=0.f; acc[i][j][1]=0.f; acc[i][j][2]=0.f; acc[i][j][3]=0.f; }
  for (int kb = 0; kb < 2; ++kb){
    const int K0 = kb * 64;
    #pragma unroll
    for (int i=0;i<8;++i){              // A: 128x64 fp32 -> bf16 LDS
      int idx = t + i*256;
      int row = idx >> 4, c4 = (idx & 15) * 4;
      float4 v = make_float4(0.f,0.f,0.f,0.f);
      if (m0 + row < M) v = *(const float4*)(A + (size_t)(m0+row)*128 + K0 + c4);
      uint2 p; p.x = packbf(v.x, v.y); p.y = packbf(v.z, v.w);
      *(uint2*)(As + row*72 + c4) = p;
    }
    #pragma unroll
    for (int i=0;i<4;++i){              // B: 128x64 bf16 copy
      int idx = t + i*256;
      int row = idx >> 3, c8 = (idx & 7) * 8;
      *(uint4*)(Bs + row*72 + c8) =
        *(const uint4*)(Bt + (size_t)(head*128 + row)*128 + K0 + c8);
    }
    __syncthreads();
    #pragma unroll
    for (int ks = 0; ks < 2; ++ks){
      short8 af[4], bfr[4];
      #pragma unroll
      for (int mi=0; mi<4; ++mi)
        af[mi] = *(const short8*)(As + (moff + mi*16 + l16)*72 + ks*32 + quad*8);
      #pragma unroll
      for (int ni=0; ni<4; ++ni)
        bfr[ni] = *(const short8*)(Bs + (noff + ni*16 + l16)*72 + ks*32 + quad*8);
      #pragma unroll
      for (int mi=0; mi<4; ++mi)
        #pragma unroll
        for (int ni=0; ni<4; ++ni)
          acc[mi][ni] = __builtin_amdgcn_mfma_f32_16x16x32_bf16(af[mi], bfr[ni], acc[mi][ni], 0,0,0);
    }
    __syncthreads();
  }
  // epilogue: bf16 repack via LDS, vectorized stores
  unsigned short* Cs = sm;                       // 128x136 bf16 (34.8 KB)
  #pragma unroll
  for (int mi=0; mi<4; ++mi)
    #pragma unroll
    for (int ni=0; ni<4; ++ni){
      int col = noff + ni*16 + l16;
      int rb  = moff + mi*16 + quad*4;
      #pragma unroll
      for (int r=0;r<4;++r) Cs[(rb+r)*136 + col] = f2bf(acc[mi][ni][r]);
    }
  __syncthreads();
  const size_t hb = (size_t)head * (size_t)M * 128;
  #pragma unroll
  for (int i=0;i<8;++i){                // FIX: 128x128/8 elems / 256 thr = 8 iters
    int e = t + i*256;
    int row = e >> 4, c8 = (e & 15) * 8;
    if (m0 + row < M)
      *(uint4*)(C + hb + (size_t)(m0+row)*128 + c8) = *(const uint4*)(Cs + row*136 + c8);
  }
}

// ---- GEMM2 (MFMA): h1 bf16 [M][512] @ W2t bf16 -> feat2b bf16 [M][64] ----
// tile 128(M) x 64(N), BK=64, 8 iters; wave w handles rows w*32..+31.
__global__ __launch_bounds__(256) void k_mm2(const unsigned short* __restrict__ A,
    const unsigned short* __restrict__ Bt,
    unsigned short* __restrict__ C, int M){
  __shared__ unsigned short sm[13824];          // As 128x72 | Bs 64x72 (27.6 KB)
  unsigned short* As = sm;
  unsigned short* Bs = sm + 9216;
  const int t = threadIdx.x;
  const int w = t >> 6, l = t & 63;
  const int quad = l >> 4, l16 = l & 15;
  const int m0 = blockIdx.x * 128;
  const int moff = w * 32;
  f32x4 acc[2][4];
  #pragma unroll
  for (int i=0;i<2;++i)
    #pragma unroll
    for (int j=0;j<4;++j){ acc[i][j][0]=0.f; acc[i][j][1]=0.f; acc[i][j][2]=0.f; acc[i][j][3]=0.f; }
  for (int kb = 0; kb < 8; ++kb){
    const int K0 = kb * 64;
    #pragma unroll
    for (int i=0;i<4;++i){
      int idx = t + i*256;
      int row = idx >> 3, c8 = (idx & 7) * 8;
      uint4 v; v.x=0u; v.y=0u; v.z=0u; v.w=0u;
      if (m0 + row < M) v = *(const uint4*)(A + (size_t)(m0+row)*512 + K0 + c8);
      *(uint4*)(As + row*72 + c8) = v;
    }
    #pragma unroll
    for (int i=0;i<2;++i){
      int idx = t + i*256;
      int row = idx >> 3, c8 = (idx & 7) * 8;
      *(uint4*)(Bs + row*72 + c8) = *(const uint4*)(Bt + (size_t)row*512 + K0 + c8);
    }
    __syncthreads();
    #pragma unroll
    for (int ks = 0; ks < 2; ++ks){
      short8 af[2], bfr[4];
      #pragma unroll
      for (int mi=0; mi<2; ++mi)
        af[mi] = *(const short8*)(As + (moff + mi*16 + l16)*72 + ks*32 + quad*8);
      #pragma unroll
      for (int ni=0; ni<4; ++ni)
        bfr[ni] = *(const short8*)(Bs + (ni*16 + l16)*72 + ks*32 + quad*8);
      #pragma unroll
      for (int mi=0; mi<2; ++mi)
        #pragma unroll
        for (int ni=0; ni<4; ++ni)
          acc[mi][ni] = __builtin_amdgcn_mfma_f32_16x16x32_bf16(af[mi], bfr[ni], acc[mi][ni], 0,0,0);
    }
    __syncthreads();
  }
  unsigned short* Cs = sm;                       // 128x72 bf16
  #pragma unroll
  for (int mi=0; mi<2; ++mi)
    #pragma unroll
    for (int ni=0; ni<4; ++ni){
      int col = ni*16 + l16;
      int rb  = moff + mi*16 + quad*4;
      #pragma unroll
      for (int r=0;r<4;++r) Cs[(rb+r)*72 + col] = f2bf(acc[mi][ni][r]);
    }
  __syncthreads();
  #pragma unroll
  for (int i=0;i<4;++i){
    int e = t + i*256;
    int row = e >> 3, c8 = (e & 7) * 8;
    if (m0 + row < M)
      *(uint4*)(C + (size_t)(m0+row)*64 + c8) = *(const uint4*)(Cs + row*72 + c8);
  }
}

// ---- layer-1 scores from head-major bf16 feat1h ----
__global__ __launch_bounds__(256) void k_score1(const unsigned short* __restrict__ feat,
    const float* __restrict__ al, const float* __restrict__ ar,
    float* __restrict__ el, float* __restrict__ er){
  int wave = threadIdx.x >> 6, lane = threadIdx.x & 63;
  int n = blockIdx.x*4 + wave;
  if (n >= N_NODES) return;
  int h = lane >> 4;
  int d = (lane & 15) * 8;
  uint4 f = *(const uint4*)(feat + (size_t)h*N_NODES*128 + (size_t)n*128 + d);
  float4 a0 = *(const float4*)(al + h*128 + d), a1 = *(const float4*)(al + h*128 + d + 4);
  float4 r0 = *(const float4*)(ar + h*128 + d), r1 = *(const float4*)(ar + h*128 + d + 4);
  float fv[8] = {bflo(f.x),bfhi(f.x),bflo(f.y),bfhi(f.y),
                 bflo(f.z),bfhi(f.z),bflo(f.w),bfhi(f.w)};
  float se = fv[0]*a0.x+fv[1]*a0.y+fv[2]*a0.z+fv[3]*a0.w
           + fv[4]*a1.x+fv[5]*a1.y+fv[6]*a1.z+fv[7]*a1.w;
  float sr = fv[0]*r0.x+fv[1]*r0.y+fv[2]*r0.z+fv[3]*r0.w
           + fv[4]*r1.x+fv[5]*r1.y+fv[6]*r1.z+fv[7]*r1.w;
  #pragma unroll
  for (int m=1;m<16;m<<=1){ se += __shfl_xor(se,m); sr += __shfl_xor(sr,m); }
  if ((lane&15)==0){ el[n*4+h]=se; er[n*4+h]=sr; }
}

// ---- layer-2 scores from bf16 feat2b ----
__global__ __launch_bounds__(256) void k_score2(const unsigned short* __restrict__ feat,
    const float* __restrict__ al, const float* __restrict__ ar,
    float* __restrict__ el, float* __restrict__ er){
  int wave = threadIdx.x >> 6, lane = threadIdx.x & 63;
  int n = blockIdx.x*4 + wave;
  if (n >= N_NODES) return;
  float v = bfus(feat[(size_t)n*64 + lane]);
  float se = v * al[lane], sr = v * ar[lane];
  #pragma unroll
  for (int m=1;m<64;m<<=1){ se += __shfl_xor(se,m); sr += __shfl_xor(sr,m); }
  if (lane==0){ el[n]=se; er[n]=sr; }
}

// ---- CSR build ----
__global__ void k_zero(int* __restrict__ p, int n){
  int i = blockIdx.x*blockDim.x + threadIdx.x;
  if (i < n) p[i] = 0;
}
__global__ void k_count(const int* __restrict__ dst, int* __restrict__ deg){
  int e = blockIdx.x*blockDim.x + threadIdx.x;
  if (e < N_EDGES) atomicAdd(&deg[dst[e]], 1);
}
__global__ __launch_bounds__(1024) void k_scan1(const int* __restrict__ deg,
    int* __restrict__ indptr, int* __restrict__ bsum){
  __shared__ int lds[1024];
  int t = threadIdx.x, i = blockIdx.x*1024 + t;
  int v = (i < N_NODES) ? deg[i] : 0;
  lds[t] = v; __syncthreads();
  for (int off=1; off<1024; off<<=1){
    int u = (t>=off)? lds[t-off] : 0;
    __syncthreads();
    lds[t] += u;
    __syncthreads();
  }
  if (i < N_NODES) indptr[i] = lds[t] - v;
  if (t == 1023) bsum[blockIdx.x] = lds[1023];
}
__global__ void k_scan2(const int* __restrict__ bsum, int* __restrict__ boff, int nb){
  __shared__ int lds[128];
  int t = threadIdx.x;
  int v = (t < nb) ? bsum[t] : 0;
  lds[t] = v; __syncthreads();
  for (int off=1; off<128; off<<=1){
    int u = (t>=off)? lds[t-off] : 0;
    __syncthreads();
    lds[t] += u;
    __syncthreads();
  }
  if (t < nb) boff[t] = lds[t] - v;
}
__global__ void k_scan3(int* __restrict__ indptr, const int* __restrict__ boff){
  int i = blockIdx.x*blockDim.x + threadIdx.x;
  if (i < N_NODES) indptr[i] += boff[i>>10];
  if (i == N_NODES) indptr[N_NODES] = N_EDGES;
}
__global__ void k_copy(const int* __restrict__ a, int* __restrict__ b){
  int i = blockIdx.x*blockDim.x + threadIdx.x;
  if (i < N_NODES) b[i] = a[i];
}
__global__ void k_scatter(const int* __restrict__ src, const int* __restrict__ dst,
                          int* __restrict__ cursor, int* __restrict__ csr_src){
  int e = blockIdx.x*blockDim.x + threadIdx.x;
  if (e < N_EDGES){
    int d = dst[e];
    int pos = atomicAdd(&cursor[d], 1);
    csr_src[pos] = src[e];
  }
}

// ---- layer-1 aggregate, head-split: grid (25000, heads). wave per (node,head). ----
// feat1h [4][N][128] bf16; half-wave (32 lanes x 8B) per edge.
__global__ __launch_bounds__(256) void k_agg1h(const unsigned short* __restrict__ feat,
    const float* __restrict__ el, const float* __restrict__ er,
    const int* __restrict__ indptr, const int* __restrict__ csr_src,
    unsigned short* __restrict__ out){
  int wave = threadIdx.x >> 6, lane = threadIdx.x & 63;
  int n = blockIdx.x*4 + wave;
  int h = blockIdx.y;
  if (n >= N_NODES) return;
  int p0 = indptr[n], p1 = indptr[n+1];
  float ern = er[n*4 + h];
  // pass 1: denominator
  float s = 0.f;
  for (int e = p0 + lane; e < p1; e += 64)
    s += __expf(lrelu(el[csr_src[e]*4 + h] + ern));
  #pragma unroll
  for (int m=1;m<64;m<<=1) s += __shfl_xor(s,m);
  float inv = s > 0.f ? 1.f/s : 0.f;
  // pass 2: half-wave per edge (256 B / edge)
  const size_t hb = (size_t)h * N_NODES * 128;
  int half = lane >> 5, hl = lane & 31;
  float a0=0.f,a1=0.f,a2=0.f,a3=0.f;
  for (int e = p0 + half; e < p1; e += 2){
    int si = csr_src[e];
    float alpha = __expf(lrelu(el[si*4 + h] + ern)) * inv;
    uint2 q = *(const uint2*)(feat + hb + (size_t)si*128 + hl*4);
    a0 += alpha*bflo(q.x); a1 += alpha*bfhi(q.x);
    a2 += alpha*bflo(q.y); a3 += alpha*bfhi(q.y);
  }
  a0 += __shfl_xor(a0,32); a1 += __shfl_xor(a1,32);
  a2 += __shfl_xor(a2,32); a3 += __shfl_xor(a3,32);
  if (half == 0){
    a0 = a0>0.f ? a0 : __expf(a0)-1.f;
    a1 = a1>0.f ? a1 : __expf(a1)-1.f;
    a2 = a2>0.f ? a2 : __expf(a2)-1.f;
    a3 = a3>0.f ? a3 : __expf(a3)-1.f;
    uint2 o; o.x = packbf(a0,a1); o.y = packbf(a2,a3);
    *(uint2*)(out + (size_t)n*512 + h*128 + hl*4) = o;
  }
}

// ---- layer-2 aggregate: wave per node, quarter-wave (16 lanes x 8B) per edge ----
__global__ __launch_bounds__(256) void k_agg2b(const unsigned short* __restrict__ feat,
    const float* __restrict__ el, const float* __restrict__ er,
    const int* __restrict__ indptr, const int* __restrict__ csr_src,
    float* __restrict__ out){
  int wave = threadIdx.x >> 6, lane = threadIdx.x & 63;
  int n = blockIdx.x*4 + wave;
  if (n >= N_NODES) return;
  int p0 = indptr[n], p1 = indptr[n+1];
  float ern = er[n];
  float s = 0.f;
  for (int e = p0 + lane; e < p1; e += 64)
    s += __expf(lrelu(el[csr_src[e]] + ern));
  #pragma unroll
  for (int m=1;m<64;m<<=1) s += __shfl_xor(s,m);
  float inv = s > 0.f ? 1.f/s : 0.f;
  int q = lane >> 4, ql = lane & 15;
  float a0=0.f,a1=0.f,a2=0.f,a3=0.f;
  for (int e = p0 + q; e < p1; e += 4){
    int si = csr_src[e];
    float alpha = __expf(lrelu(el[si] + ern)) * inv;
    uint2 v = *(const uint2*)(feat + (size_t)si*64 + ql*4);
    a0 += alpha*bflo(v.x); a1 += alpha*bfhi(v.x);
    a2 += alpha*bflo(v.y); a3 += alpha*bfhi(v.y);
  }
  a0 += __shfl_xor(a0,16); a1 += __shfl_xor(a1,16);
  a2 += __shfl_xor(a2,16); a3 += __shfl_xor(a3,16);
  a0 += __shfl_xor(a0,32); a1 += __shfl_xor(a1,32);
  a2 += __shfl_xor(a2,32); a3 += __shfl_xor(a3,32);
  if (lane < 16)
    *(float4*)(out + (size_t)n*64 + ql*4) = make_float4(a0,a1,a2,a3);
}

extern "C" void kernel_launch(void* const* d_in, const int* in_sizes, int n_in,
                              void* d_out, int out_size, void* d_ws, size_t ws_size,
                              hipStream_t stream){
  const float* x   = (const float*)d_in[0];
  const float* W1  = (const float*)d_in[1];
  const float* al1 = (const float*)d_in[2];
  const float* ar1 = (const float*)d_in[3];
  const float* W2  = (const float*)d_in[4];
  const float* al2 = (const float*)d_in[5];
  const float* ar2 = (const float*)d_in[6];
  const int* src   = (const int*)d_in[7];
  const int* dst   = (const int*)d_in[8];
  float* out = (float*)d_out;

  char* ws = (char*)d_ws;
  size_t off = 0;
  auto alloc = [&](size_t bytes)->char*{
    char* p = ws + off; off += (bytes + 255) & ~(size_t)255; return p;
  };
  unsigned short* feat1h = (unsigned short*)alloc((size_t)4*N_NODES*128*2); // 102.4 MB
  unsigned short* h1     = (unsigned short*)alloc((size_t)N_NODES*512*2);   // 102.4 MB
  unsigned short* feat2b = feat1h;            // alias: feat1h dead after k_agg1h
  unsigned short* W1t = (unsigned short*)alloc(512*128*2);
  unsigned short* W2t = (unsigned short*)alloc(64*512*2);
  float* el1 = (float*)alloc((size_t)N_NODES*4*4);
  float* er1 = (float*)alloc((size_t)N_NODES*4*4);
  float* el2 = el1;                           // alias: el1 dead after k_agg1h
  float* er2 = er1;
  int* deg     = (int*)alloc((size_t)N_NODES*4);
  int* indptr  = (int*)alloc((size_t)(N_NODES+1)*4);
  int* cursor  = (int*)alloc((size_t)N_NODES*4);
  int* bsum    = (int*)alloc(512);
  int* boff    = (int*)alloc(512);
  int* csr_src = (int*)alloc((size_t)N_EDGES*4);                            // 12.8 MB
  // total ~222 MB (same footprint proven in rounds 2-3)

  dim3 b256(256);
  k_zero<<<dim3((N_NODES+255)/256), b256, 0, stream>>>(deg, N_NODES);
  k_cvtW1<<<dim3(256), b256, 0, stream>>>(W1, W1t);
  k_cvtW2<<<dim3(128), b256, 0, stream>>>(W2, W2t);
  // layer 1 projection (MFMA)
  k_mm1<<<dim3(782, 4), b256, 0, stream>>>(x, W1t, feat1h, N_NODES);
  k_score1<<<dim3(25000), b256, 0, stream>>>(feat1h, al1, ar1, el1, er1);
  // dst-CSR
  k_count<<<dim3((N_EDGES+255)/256), b256, 0, stream>>>(dst, deg);
  k_scan1<<<dim3(98), dim3(1024), 0, stream>>>(deg, indptr, bsum);
  k_scan2<<<dim3(1), dim3(128), 0, stream>>>(bsum, boff, 98);
  k_scan3<<<dim3((N_NODES+256)/256), b256, 0, stream>>>(indptr, boff);
  k_copy<<<dim3((N_NODES+255)/256), b256, 0, stream>>>(indptr, cursor);
  k_scatter<<<dim3((N_EDGES+255)/256), b256, 0, stream>>>(src, dst, cursor, csr_src);
  // layer-1 aggregate + ELU (head-phased for L3 residency)
  k_agg1h<<<dim3(25000, 4), b256, 0, stream>>>(feat1h, el1, er1, indptr, csr_src, h1);
  // layer 2
  k_mm2<<<dim3(782), b256, 0, stream>>>(h1, W2t, feat2b, N_NODES);
  k_score2<<<dim3(25000), b256, 0, stream>>>(feat2b, al2, ar2, el2, er2);
  k_agg2b<<<dim3(25000), b256, 0, stream>>>(feat2b, el2, er2, indptr, csr_src, out);
}

// Round 6
// 1153.020 us; speedup vs baseline: 1.3957x; 1.2838x over previous
//
#include <hip/hip_runtime.h>
#include <math.h>

#define N_NODES 100000
#define N_EDGES 3200000
#define NEG 0.2f

typedef __attribute__((ext_vector_type(8))) short short8;
typedef __attribute__((ext_vector_type(4))) float f32x4;

__device__ __forceinline__ float lrelu(float x){ return x > 0.f ? x : NEG * x; }
__device__ __forceinline__ float bflo(unsigned int u){
  union { unsigned int i; float f; } v; v.i = u << 16; return v.f;
}
__device__ __forceinline__ float bfhi(unsigned int u){
  union { unsigned int i; float f; } v; v.i = u & 0xffff0000u; return v.f;
}
__device__ __forceinline__ float bfus(unsigned short u){
  union { unsigned int i; float f; } v; v.i = ((unsigned int)u) << 16; return v.f;
}
__device__ __forceinline__ unsigned short f2bf(float f){
  union { float f; unsigned int i; } v; v.f = f;
  unsigned int r = v.i + 0x7fffu + ((v.i >> 16) & 1u);
  return (unsigned short)(r >> 16);
}
__device__ __forceinline__ unsigned int packbf(float lo, float hi){
  return (unsigned int)f2bf(lo) | ((unsigned int)f2bf(hi) << 16);
}

// ---- weight prep: W1 [128][512] fp32 -> W1t [512][128] bf16 (n-major) ----
__global__ void k_cvtW1(const float* __restrict__ W, unsigned short* __restrict__ Wt){
  int i = blockIdx.x*256 + threadIdx.x;
  if (i < 512*128){ int n = i >> 7, k = i & 127; Wt[i] = f2bf(W[k*512 + n]); }
}
// ---- W2 [512][64] fp32 -> W2t [64][512] bf16 ----
__global__ void k_cvtW2(const float* __restrict__ W, unsigned short* __restrict__ Wt){
  int i = blockIdx.x*256 + threadIdx.x;
  if (i < 64*512){ int n = i >> 9, k = i & 511; Wt[i] = f2bf(W[k*64 + n]); }
}

// ---- GEMM1 (MFMA): x fp32 [M][128] @ W1t bf16 -> feat1 bf16 [M][512] node-major ----
// block 256 (4 waves), tile 128(M) x 128(N); N-tile == one head (blockIdx.y).
__global__ __launch_bounds__(256) void k_mm1(const float* __restrict__ A,
    const unsigned short* __restrict__ Bt,
    unsigned short* __restrict__ C, int M){
  __shared__ unsigned short sm[18432];          // As 128x72 | Bs 128x72 (36.9 KB)
  unsigned short* As = sm;
  unsigned short* Bs = sm + 9216;
  const int t = threadIdx.x;
  const int w = t >> 6, l = t & 63;
  const int quad = l >> 4, l16 = l & 15;
  const int m0 = blockIdx.x * 128;
  const int head = blockIdx.y;
  const int moff = (w & 1) * 64, noff = (w >> 1) * 64;
  f32x4 acc[4][4];
  #pragma unroll
  for (int i=0;i<4;++i)
    #pragma unroll
    for (int j=0;j<4;++j){ acc[i][j][0]=0.f; acc[i][j][1]=0.f; acc[i][j][2]=0.f; acc[i][j][3]=0.f; }
  for (int kb = 0; kb < 2; ++kb){
    const int K0 = kb * 64;
    #pragma unroll
    for (int i=0;i<8;++i){              // A: 128x64 fp32 -> bf16 LDS
      int idx = t + i*256;
      int row = idx >> 4, c4 = (idx & 15) * 4;
      float4 v = make_float4(0.f,0.f,0.f,0.f);
      if (m0 + row < M) v = *(const float4*)(A + (size_t)(m0+row)*128 + K0 + c4);
      uint2 p; p.x = packbf(v.x, v.y); p.y = packbf(v.z, v.w);
      *(uint2*)(As + row*72 + c4) = p;
    }
    #pragma unroll
    for (int i=0;i<4;++i){              // B: 128x64 bf16 copy
      int idx = t + i*256;
      int row = idx >> 3, c8 = (idx & 7) * 8;
      *(uint4*)(Bs + row*72 + c8) =
        *(const uint4*)(Bt + (size_t)(head*128 + row)*128 + K0 + c8);
    }
    __syncthreads();
    #pragma unroll
    for (int ks = 0; ks < 2; ++ks){
      short8 af[4], bfr[4];
      #pragma unroll
      for (int mi=0; mi<4; ++mi)
        af[mi] = *(const short8*)(As + (moff + mi*16 + l16)*72 + ks*32 + quad*8);
      #pragma unroll
      for (int ni=0; ni<4; ++ni)
        bfr[ni] = *(const short8*)(Bs + (noff + ni*16 + l16)*72 + ks*32 + quad*8);
      #pragma unroll
      for (int mi=0; mi<4; ++mi)
        #pragma unroll
        for (int ni=0; ni<4; ++ni)
          acc[mi][ni] = __builtin_amdgcn_mfma_f32_16x16x32_bf16(af[mi], bfr[ni], acc[mi][ni], 0,0,0);
    }
    __syncthreads();
  }
  // epilogue: bf16 repack via LDS, vectorized node-major stores
  unsigned short* Cs = sm;                       // 128x136 bf16 (34.8 KB)
  #pragma unroll
  for (int mi=0; mi<4; ++mi)
    #pragma unroll
    for (int ni=0; ni<4; ++ni){
      int col = noff + ni*16 + l16;
      int rb  = moff + mi*16 + quad*4;
      #pragma unroll
      for (int r=0;r<4;++r) Cs[(rb+r)*136 + col] = f2bf(acc[mi][ni][r]);
    }
  __syncthreads();
  const int hcol = head * 128;
  #pragma unroll
  for (int i=0;i<8;++i){                // 128x128 elems / 8 per-thread / 256 thr = 8
    int e = t + i*256;
    int row = e >> 4, c8 = (e & 15) * 8;
    if (m0 + row < M)
      *(uint4*)(C + (size_t)(m0+row)*512 + hcol + c8) = *(const uint4*)(Cs + row*136 + c8);
  }
}

// ---- GEMM2 (MFMA): h1 bf16 [M][512] @ W2t bf16 -> feat2b bf16 [M][64] ----
__global__ __launch_bounds__(256) void k_mm2(const unsigned short* __restrict__ A,
    const unsigned short* __restrict__ Bt,
    unsigned short* __restrict__ C, int M){
  __shared__ unsigned short sm[13824];          // As 128x72 | Bs 64x72 (27.6 KB)
  unsigned short* As = sm;
  unsigned short* Bs = sm + 9216;
  const int t = threadIdx.x;
  const int w = t >> 6, l = t & 63;
  const int quad = l >> 4, l16 = l & 15;
  const int m0 = blockIdx.x * 128;
  const int moff = w * 32;
  f32x4 acc[2][4];
  #pragma unroll
  for (int i=0;i<2;++i)
    #pragma unroll
    for (int j=0;j<4;++j){ acc[i][j][0]=0.f; acc[i][j][1]=0.f; acc[i][j][2]=0.f; acc[i][j][3]=0.f; }
  for (int kb = 0; kb < 8; ++kb){
    const int K0 = kb * 64;
    #pragma unroll
    for (int i=0;i<4;++i){
      int idx = t + i*256;
      int row = idx >> 3, c8 = (idx & 7) * 8;
      uint4 v; v.x=0u; v.y=0u; v.z=0u; v.w=0u;
      if (m0 + row < M) v = *(const uint4*)(A + (size_t)(m0+row)*512 + K0 + c8);
      *(uint4*)(As + row*72 + c8) = v;
    }
    #pragma unroll
    for (int i=0;i<2;++i){
      int idx = t + i*256;
      int row = idx >> 3, c8 = (idx & 7) * 8;
      *(uint4*)(Bs + row*72 + c8) = *(const uint4*)(Bt + (size_t)row*512 + K0 + c8);
    }
    __syncthreads();
    #pragma unroll
    for (int ks = 0; ks < 2; ++ks){
      short8 af[2], bfr[4];
      #pragma unroll
      for (int mi=0; mi<2; ++mi)
        af[mi] = *(const short8*)(As + (moff + mi*16 + l16)*72 + ks*32 + quad*8);
      #pragma unroll
      for (int ni=0; ni<4; ++ni)
        bfr[ni] = *(const short8*)(Bs + (ni*16 + l16)*72 + ks*32 + quad*8);
      #pragma unroll
      for (int mi=0; mi<2; ++mi)
        #pragma unroll
        for (int ni=0; ni<4; ++ni)
          acc[mi][ni] = __builtin_amdgcn_mfma_f32_16x16x32_bf16(af[mi], bfr[ni], acc[mi][ni], 0,0,0);
    }
    __syncthreads();
  }
  unsigned short* Cs = sm;                       // 128x72 bf16
  #pragma unroll
  for (int mi=0; mi<2; ++mi)
    #pragma unroll
    for (int ni=0; ni<4; ++ni){
      int col = ni*16 + l16;
      int rb  = moff + mi*16 + quad*4;
      #pragma unroll
      for (int r=0;r<4;++r) Cs[(rb+r)*72 + col] = f2bf(acc[mi][ni][r]);
    }
  __syncthreads();
  #pragma unroll
  for (int i=0;i<4;++i){
    int e = t + i*256;
    int row = e >> 3, c8 = (e & 7) * 8;
    if (m0 + row < M)
      *(uint4*)(C + (size_t)(m0+row)*64 + c8) = *(const uint4*)(Cs + row*72 + c8);
  }
}

// ---- layer-1 scores: el/er (N,4) from node-major bf16 feat (N,512) ----
__global__ __launch_bounds__(256) void k_score1(const unsigned short* __restrict__ feat,
    const float* __restrict__ al, const float* __restrict__ ar,
    float* __restrict__ el, float* __restrict__ er){
  int wave = threadIdx.x >> 6, lane = threadIdx.x & 63;
  int n = blockIdx.x*4 + wave;
  if (n >= N_NODES) return;
  int h = lane >> 4;
  int d = h*128 + (lane & 15)*8;
  uint4 f = *(const uint4*)(feat + (size_t)n*512 + d);
  float4 a0 = *(const float4*)(al + d), a1 = *(const float4*)(al + d + 4);
  float4 r0 = *(const float4*)(ar + d), r1 = *(const float4*)(ar + d + 4);
  float fv[8] = {bflo(f.x),bfhi(f.x),bflo(f.y),bfhi(f.y),
                 bflo(f.z),bfhi(f.z),bflo(f.w),bfhi(f.w)};
  float se = fv[0]*a0.x+fv[1]*a0.y+fv[2]*a0.z+fv[3]*a0.w
           + fv[4]*a1.x+fv[5]*a1.y+fv[6]*a1.z+fv[7]*a1.w;
  float sr = fv[0]*r0.x+fv[1]*r0.y+fv[2]*r0.z+fv[3]*r0.w
           + fv[4]*r1.x+fv[5]*r1.y+fv[6]*r1.z+fv[7]*r1.w;
  #pragma unroll
  for (int m=1;m<16;m<<=1){ se += __shfl_xor(se,m); sr += __shfl_xor(sr,m); }
  if ((lane&15)==0){ el[n*4+h]=se; er[n*4+h]=sr; }
}

// ---- layer-2 scores from bf16 feat2b ----
__global__ __launch_bounds__(256) void k_score2(const unsigned short* __restrict__ feat,
    const float* __restrict__ al, const float* __restrict__ ar,
    float* __restrict__ el, float* __restrict__ er){
  int wave = threadIdx.x >> 6, lane = threadIdx.x & 63;
  int n = blockIdx.x*4 + wave;
  if (n >= N_NODES) return;
  float v = bfus(feat[(size_t)n*64 + lane]);
  float se = v * al[lane], sr = v * ar[lane];
  #pragma unroll
  for (int m=1;m<64;m<<=1){ se += __shfl_xor(se,m); sr += __shfl_xor(sr,m); }
  if (lane==0){ el[n]=se; er[n]=sr; }
}

// ---- CSR build ----
__global__ void k_zero(int* __restrict__ p, int n){
  int i = blockIdx.x*blockDim.x + threadIdx.x;
  if (i < n) p[i] = 0;
}
__global__ void k_count(const int* __restrict__ dst, int* __restrict__ deg){
  int e = blockIdx.x*blockDim.x + threadIdx.x;
  if (e < N_EDGES) atomicAdd(&deg[dst[e]], 1);
}
__global__ __launch_bounds__(1024) void k_scan1(const int* __restrict__ deg,
    int* __restrict__ indptr, int* __restrict__ bsum){
  __shared__ int lds[1024];
  int t = threadIdx.x, i = blockIdx.x*1024 + t;
  int v = (i < N_NODES) ? deg[i] : 0;
  lds[t] = v; __syncthreads();
  for (int off=1; off<1024; off<<=1){
    int u = (t>=off)? lds[t-off] : 0;
    __syncthreads();
    lds[t] += u;
    __syncthreads();
  }
  if (i < N_NODES) indptr[i] = lds[t] - v;
  if (t == 1023) bsum[blockIdx.x] = lds[1023];
}
__global__ void k_scan2(const int* __restrict__ bsum, int* __restrict__ boff, int nb){
  __shared__ int lds[128];
  int t = threadIdx.x;
  int v = (t < nb) ? bsum[t] : 0;
  lds[t] = v; __syncthreads();
  for (int off=1; off<128; off<<=1){
    int u = (t>=off)? lds[t-off] : 0;
    __syncthreads();
    lds[t] += u;
    __syncthreads();
  }
  if (t < nb) boff[t] = lds[t] - v;
}
__global__ void k_scan3(int* __restrict__ indptr, const int* __restrict__ boff){
  int i = blockIdx.x*blockDim.x + threadIdx.x;
  if (i < N_NODES) indptr[i] += boff[i>>10];
  if (i == N_NODES) indptr[N_NODES] = N_EDGES;
}
__global__ void k_copy(const int* __restrict__ a, int* __restrict__ b){
  int i = blockIdx.x*blockDim.x + threadIdx.x;
  if (i < N_NODES) b[i] = a[i];
}
__global__ void k_scatter(const int* __restrict__ src, const int* __restrict__ dst,
                          int* __restrict__ cursor, int* __restrict__ csr_src){
  int e = blockIdx.x*blockDim.x + threadIdx.x;
  if (e < N_EDGES){
    int d = dst[e];
    int pos = atomicAdd(&cursor[d], 1);
    csr_src[pos] = src[e];
  }
}

// ---- layer-1 aggregate + ELU: ONE-PASS online softmax, wave per node ----
// feat node-major [N][512] bf16; lane covers 8 dims of head (lane>>4); every
// lane sees every edge, so ssum needs no cross-lane reduction.
__global__ __launch_bounds__(256) void k_agg1(const unsigned short* __restrict__ feat,
    const float* __restrict__ el, const float* __restrict__ er,
    const int* __restrict__ indptr, const int* __restrict__ csr_src,
    unsigned short* __restrict__ out){
  int wave = threadIdx.x >> 6, lane = threadIdx.x & 63;
  int n = blockIdx.x*4 + wave;
  if (n >= N_NODES) return;
  int p0 = indptr[n], p1 = indptr[n+1];
  const int hh = lane >> 4;
  const int d0 = lane * 8;
  const float myer = er[n*4 + hh];
  float ssum = 0.f;
  float acc[8] = {0.f,0.f,0.f,0.f,0.f,0.f,0.f,0.f};
  int e = p0;
  for (; e + 1 < p1; e += 2){
    int s0 = csr_src[e], s1 = csr_src[e+1];
    float w0 = __expf(lrelu(el[s0*4 + hh] + myer));
    float w1 = __expf(lrelu(el[s1*4 + hh] + myer));
    uint4 q0 = *(const uint4*)(feat + (size_t)s0*512 + d0);
    uint4 q1 = *(const uint4*)(feat + (size_t)s1*512 + d0);
    ssum += w0 + w1;
    acc[0] += w0*bflo(q0.x) + w1*bflo(q1.x);
    acc[1] += w0*bfhi(q0.x) + w1*bfhi(q1.x);
    acc[2] += w0*bflo(q0.y) + w1*bflo(q1.y);
    acc[3] += w0*bfhi(q0.y) + w1*bfhi(q1.y);
    acc[4] += w0*bflo(q0.z) + w1*bflo(q1.z);
    acc[5] += w0*bfhi(q0.z) + w1*bfhi(q1.z);
    acc[6] += w0*bflo(q0.w) + w1*bflo(q1.w);
    acc[7] += w0*bfhi(q0.w) + w1*bfhi(q1.w);
  }
  if (e < p1){
    int s0 = csr_src[e];
    float w0 = __expf(lrelu(el[s0*4 + hh] + myer));
    uint4 q0 = *(const uint4*)(feat + (size_t)s0*512 + d0);
    ssum += w0;
    acc[0] += w0*bflo(q0.x); acc[1] += w0*bfhi(q0.x);
    acc[2] += w0*bflo(q0.y); acc[3] += w0*bfhi(q0.y);
    acc[4] += w0*bflo(q0.z); acc[5] += w0*bfhi(q0.z);
    acc[6] += w0*bflo(q0.w); acc[7] += w0*bfhi(q0.w);
  }
  float inv = ssum > 0.f ? 1.f/ssum : 0.f;
  #pragma unroll
  for (int i=0;i<8;++i){
    float v = acc[i] * inv;
    acc[i] = v > 0.f ? v : __expf(v) - 1.f;   // fused ELU
  }
  uint4 o;
  o.x = packbf(acc[0],acc[1]); o.y = packbf(acc[2],acc[3]);
  o.z = packbf(acc[4],acc[5]); o.w = packbf(acc[6],acc[7]);
  *(uint4*)(out + (size_t)n*512 + d0) = o;
}

// ---- layer-2 aggregate: ONE-PASS, wave per node, eighth-wave per edge ----
// feat2b bf16 [N][64] (128 B/row); 8 lanes x 16 B cover a row; 8 edges in flight.
__global__ __launch_bounds__(256) void k_agg2(const unsigned short* __restrict__ feat,
    const float* __restrict__ el, const float* __restrict__ er,
    const int* __restrict__ indptr, const int* __restrict__ csr_src,
    float* __restrict__ out){
  int wave = threadIdx.x >> 6, lane = threadIdx.x & 63;
  int n = blockIdx.x*4 + wave;
  if (n >= N_NODES) return;
  int p0 = indptr[n], p1 = indptr[n+1];
  float ern = er[n];
  int g = lane >> 3, ql = lane & 7;
  float s = 0.f;
  float acc[8] = {0.f,0.f,0.f,0.f,0.f,0.f,0.f,0.f};
  for (int e = p0 + g; e < p1; e += 8){
    int si = csr_src[e];
    float w = __expf(lrelu(el[si] + ern));
    uint4 v = *(const uint4*)(feat + (size_t)si*64 + ql*8);
    s += w;
    acc[0] += w*bflo(v.x); acc[1] += w*bfhi(v.x);
    acc[2] += w*bflo(v.y); acc[3] += w*bfhi(v.y);
    acc[4] += w*bflo(v.z); acc[5] += w*bfhi(v.z);
    acc[6] += w*bflo(v.w); acc[7] += w*bfhi(v.w);
  }
  #pragma unroll
  for (int m=8;m<64;m<<=1){
    s += __shfl_xor(s,m);
    #pragma unroll
    for (int i=0;i<8;++i) acc[i] += __shfl_xor(acc[i],m);
  }
  float inv = s > 0.f ? 1.f/s : 0.f;
  if (g == 0){
    float* op = out + (size_t)n*64 + ql*8;
    *(float4*)op     = make_float4(acc[0]*inv, acc[1]*inv, acc[2]*inv, acc[3]*inv);
    *(float4*)(op+4) = make_float4(acc[4]*inv, acc[5]*inv, acc[6]*inv, acc[7]*inv);
  }
}

extern "C" void kernel_launch(void* const* d_in, const int* in_sizes, int n_in,
                              void* d_out, int out_size, void* d_ws, size_t ws_size,
                              hipStream_t stream){
  const float* x   = (const float*)d_in[0];
  const float* W1  = (const float*)d_in[1];
  const float* al1 = (const float*)d_in[2];
  const float* ar1 = (const float*)d_in[3];
  const float* W2  = (const float*)d_in[4];
  const float* al2 = (const float*)d_in[5];
  const float* ar2 = (const float*)d_in[6];
  const int* src   = (const int*)d_in[7];
  const int* dst   = (const int*)d_in[8];
  float* out = (float*)d_out;

  char* ws = (char*)d_ws;
  size_t off = 0;
  auto alloc = [&](size_t bytes)->char*{
    char* p = ws + off; off += (bytes + 255) & ~(size_t)255; return p;
  };
  unsigned short* feat1 = (unsigned short*)alloc((size_t)N_NODES*512*2);  // 102.4 MB
  unsigned short* h1    = (unsigned short*)alloc((size_t)N_NODES*512*2);  // 102.4 MB
  unsigned short* feat2b = feat1;             // alias: feat1 dead after k_agg1
  unsigned short* W1t = (unsigned short*)alloc(512*128*2);
  unsigned short* W2t = (unsigned short*)alloc(64*512*2);
  float* el1 = (float*)alloc((size_t)N_NODES*4*4);
  float* er1 = (float*)alloc((size_t)N_NODES*4*4);
  float* el2 = el1;                           // alias: el1 dead after k_agg1
  float* er2 = er1;
  int* deg     = (int*)alloc((size_t)N_NODES*4);
  int* indptr  = (int*)alloc((size_t)(N_NODES+1)*4);
  int* cursor  = (int*)alloc((size_t)N_NODES*4);
  int* bsum    = (int*)alloc(512);
  int* boff    = (int*)alloc(512);
  int* csr_src = (int*)alloc((size_t)N_EDGES*4);                          // 12.8 MB
  // total ~222 MB (footprint proven in rounds 3/5)

  dim3 b256(256);
  k_zero<<<dim3((N_NODES+255)/256), b256, 0, stream>>>(deg, N_NODES);
  k_cvtW1<<<dim3(256), b256, 0, stream>>>(W1, W1t);
  k_cvtW2<<<dim3(128), b256, 0, stream>>>(W2, W2t);
  // layer 1 projection (MFMA, node-major out)
  k_mm1<<<dim3(782, 4), b256, 0, stream>>>(x, W1t, feat1, N_NODES);
  k_score1<<<dim3(25000), b256, 0, stream>>>(feat1, al1, ar1, el1, er1);
  // dst-CSR
  k_count<<<dim3((N_EDGES+255)/256), b256, 0, stream>>>(dst, deg);
  k_scan1<<<dim3(98), dim3(1024), 0, stream>>>(deg, indptr, bsum);
  k_scan2<<<dim3(1), dim3(128), 0, stream>>>(bsum, boff, 98);
  k_scan3<<<dim3((N_NODES+256)/256), b256, 0, stream>>>(indptr, boff);
  k_copy<<<dim3((N_NODES+255)/256), b256, 0, stream>>>(indptr, cursor);
  k_scatter<<<dim3((N_EDGES+255)/256), b256, 0, stream>>>(src, dst, cursor, csr_src);
  // layer-1 aggregate + ELU (single-pass online softmax)
  k_agg1<<<dim3(25000), b256, 0, stream>>>(feat1, el1, er1, indptr, csr_src, h1);
  // layer 2
  k_mm2<<<dim3(782), b256, 0, stream>>>(h1, W2t, feat2b, N_NODES);
  k_score2<<<dim3(25000), b256, 0, stream>>>(feat2b, al2, ar2, el2, er2);
  k_agg2<<<dim3(25000), b256, 0, stream>>>(feat2b, el2, er2, indptr, csr_src, out);
}